// Round 1
// baseline (667.620 us; speedup 1.0000x reference)
//
#include <hip/hip_runtime.h>

typedef unsigned short u16;
typedef unsigned int u32;

typedef __bf16 bf16x8 __attribute__((ext_vector_type(8)));
typedef float f32x4 __attribute__((ext_vector_type(4)));

__device__ __forceinline__ u16 f2bf(float f) {
  u32 u = __float_as_uint(f);
  u = u + 0x7fffu + ((u >> 16) & 1u);
  return (u16)(u >> 16);
}
__device__ __forceinline__ float bf2f(u16 u) {
  return __uint_as_float(((u32)u) << 16);
}

// strict-< insertion keeps earliest index on ties (matches jax.lax.top_k)
__device__ __forceinline__ void ins3(float d, int s,
                                     float& d0, float& d1, float& d2,
                                     int& i0, int& i1, int& i2) {
  if (d < d2) {
    if (d < d1) {
      d2 = d1; i2 = i1;
      if (d < d0) { d1 = d0; i1 = i0; d0 = d; i0 = s; }
      else        { d1 = d; i1 = s; }
    } else { d2 = d; i2 = s; }
  }
}

// ---------------------------------------------------------------- weights->bf16
__global__ __launch_bounds__(256) void conv_w_kernel(
    const float* __restrict__ W1, const float* __restrict__ W2,
    u16* __restrict__ W1b, u16* __restrict__ W2b) {
  int i = blockIdx.x * 256 + threadIdx.x;      // 512 blocks * 256 = 131072 exactly
  if (i < 98304) W1b[i] = f2bf(W1[i]);
  else           W2b[i - 98304] = f2bf(W2[i - 98304]);
}

// ---------------------------------------------------------------- 3NN + interp
// Block: 256 threads = 64 target points x 4 sub-scans of 256 sources.
// Grid: 16 batches * 64 = 1024 blocks.
__global__ __launch_bounds__(256) void interp_kernel(
    const float* __restrict__ txyz, const float* __restrict__ sxyz,
    const float* __restrict__ sfeat, const float* __restrict__ skip,
    u16* __restrict__ Xb) {
  __shared__ float4 sP[1024];      // x,y,z,r2
  __shared__ float  md[64 * 12];
  __shared__ int    mi[64 * 12];
  __shared__ float  fw[64 * 3];
  __shared__ int    fi[64 * 3];

  const int t = threadIdx.x;
  const int blk = blockIdx.x;
  const int b = blk >> 6;
  const int n0 = (blk & 63) << 6;

  const float* sb = sxyz + (size_t)b * 1024 * 3;
  for (int i = t; i < 1024; i += 256) {
    float x = sb[i * 3 + 0], y = sb[i * 3 + 1], z = sb[i * 3 + 2];
    float r2 = __fadd_rn(__fadd_rn(__fmul_rn(x, x), __fmul_rn(y, y)), __fmul_rn(z, z));
    sP[i] = make_float4(x, y, z, r2);
  }
  __syncthreads();

  const int p = t >> 2, sub = t & 3;
  const int n = n0 + p;
  const float* tb = txyz + ((size_t)b * 4096 + n) * 3;
  const float t0 = tb[0], t1 = tb[1], t2 = tb[2];
  const float q2 = __fadd_rn(__fadd_rn(__fmul_rn(t0, t0), __fmul_rn(t1, t1)), __fmul_rn(t2, t2));

  float d0 = 1e30f, d1 = 1e30f, d2 = 1e30f;
  int i0 = 0, i1 = 0, i2 = 0;
  const int sbeg = sub * 256;
  for (int s = sbeg; s < sbeg + 256; ++s) {
    float4 sp = sP[s];
    float c = __fmul_rn(t0, sp.x);
    c = __fadd_rn(c, __fmul_rn(t1, sp.y));
    c = __fadd_rn(c, __fmul_rn(t2, sp.z));
    // matches ref: (q2 + r2) - 2*cross, then max(.,0); no FMA contraction
    float d = __fadd_rn(__fadd_rn(q2, sp.w), __fmul_rn(-2.0f, c));
    d = fmaxf(d, 0.0f);
    ins3(d, s, d0, d1, d2, i0, i1, i2);
  }
  md[p * 12 + sub * 3 + 0] = d0; md[p * 12 + sub * 3 + 1] = d1; md[p * 12 + sub * 3 + 2] = d2;
  mi[p * 12 + sub * 3 + 0] = i0; mi[p * 12 + sub * 3 + 1] = i1; mi[p * 12 + sub * 3 + 2] = i2;
  __syncthreads();

  if (sub == 0) {
    float D0 = 1e30f, D1 = 1e30f, D2 = 1e30f;
    int I0 = 0, I1 = 0, I2 = 0;
    for (int ss = 0; ss < 4; ++ss)
      for (int k = 0; k < 3; ++k)
        ins3(md[p * 12 + ss * 3 + k], mi[p * 12 + ss * 3 + k], D0, D1, D2, I0, I1, I2);
    int idxs[3] = {I0, I1, I2};
    float w[3], wsum = 0.f;
    for (int k = 0; k < 3; ++k) {
      float4 sp = sP[idxs[k]];
      float dx = t0 - sp.x, dy = t1 - sp.y, dz = t2 - sp.z;
      float dd = __fadd_rn(__fadd_rn(__fmul_rn(dx, dx), __fmul_rn(dy, dy)), __fmul_rn(dz, dz));
      w[k] = 1.0f / (dd + 1e-8f);
      wsum += w[k];
    }
    for (int k = 0; k < 3; ++k) {
      fi[p * 3 + k] = idxs[k];
      fw[p * 3 + k] = w[k] / wsum;
    }
  }
  __syncthreads();

  // phase 2: coalesced gather+blend, one point per iteration, thread=channel
  const float* fb = sfeat + (size_t)b * 1024 * 256;
  const size_t rowbase = (size_t)b * 4096 + n0;
  for (int pp = 0; pp < 64; ++pp) {
    int j0 = fi[pp * 3 + 0], j1 = fi[pp * 3 + 1], j2 = fi[pp * 3 + 2];
    float w0 = fw[pp * 3 + 0], w1 = fw[pp * 3 + 1], w2 = fw[pp * 3 + 2];
    float f = w0 * fb[j0 * 256 + t] + w1 * fb[j1 * 256 + t] + w2 * fb[j2 * 256 + t];
    size_t ro = (rowbase + pp) * 384;
    Xb[ro + t] = f2bf(f);
    if (t < 128) Xb[ro + 256 + t] = f2bf(skip[(rowbase + pp) * 128 + t]);
  }
}

// ---------------------------------------------------------------- GEMM1: Y1 = X(65536x384) * W1^T(256x384), bf16 MFMA, + column stats
__global__ __launch_bounds__(256) void gemm1_kernel(
    const u16* __restrict__ X, const u16* __restrict__ Wb,
    u16* __restrict__ Y, float* __restrict__ ps, float* __restrict__ pq) {
  const int K = 384;
  __shared__ u16 As[128 * 40];
  __shared__ u16 Bs[128 * 40];
  __shared__ float csum[128];
  __shared__ float csq[128];

  const int t = threadIdx.x;
  const int bm = blockIdx.x, bn = blockIdx.y;
  const int w = t >> 6, l = t & 63;
  const int wm = w >> 1, wn = w & 1;
  const int lm = l & 15, q = l >> 4;
  const int m0 = t >> 2, qq = t & 3;

  f32x4 acc[4][4] = {};

  const u16* Ag = X + (size_t)bm * 128 * K;
  const u16* Bg = Wb + (size_t)bn * 128 * K;

  for (int k0 = 0; k0 < K; k0 += 32) {
    uint4 av0 = *(const uint4*)(Ag + (size_t)m0 * K + k0 + qq * 8);
    uint4 av1 = *(const uint4*)(Ag + (size_t)(m0 + 64) * K + k0 + qq * 8);
    uint4 bv0 = *(const uint4*)(Bg + (size_t)m0 * K + k0 + qq * 8);
    uint4 bv1 = *(const uint4*)(Bg + (size_t)(m0 + 64) * K + k0 + qq * 8);
    __syncthreads();
    *(uint4*)&As[m0 * 40 + qq * 8] = av0;
    *(uint4*)&As[(m0 + 64) * 40 + qq * 8] = av1;
    *(uint4*)&Bs[m0 * 40 + qq * 8] = bv0;
    *(uint4*)&Bs[(m0 + 64) * 40 + qq * 8] = bv1;
    __syncthreads();
    bf16x8 af[4], bfv[4];
#pragma unroll
    for (int i = 0; i < 4; ++i)
      af[i] = *(const bf16x8*)&As[(wm * 64 + i * 16 + lm) * 40 + q * 8];
#pragma unroll
    for (int j = 0; j < 4; ++j)
      bfv[j] = *(const bf16x8*)&Bs[(wn * 64 + j * 16 + lm) * 40 + q * 8];
#pragma unroll
    for (int i = 0; i < 4; ++i)
#pragma unroll
      for (int j = 0; j < 4; ++j)
        acc[i][j] = __builtin_amdgcn_mfma_f32_16x16x32_bf16(af[i], bfv[j], acc[i][j], 0, 0, 0);
  }

  if (t < 128) { csum[t] = 0.f; csq[t] = 0.f; }
  __syncthreads();

  float lsum[4] = {0, 0, 0, 0}, lsq[4] = {0, 0, 0, 0};
  const int colb = bn * 128 + wn * 64;
#pragma unroll
  for (int i = 0; i < 4; ++i) {
    const int mg = bm * 128 + wm * 64 + i * 16 + q * 4;
#pragma unroll
    for (int r = 0; r < 4; ++r) {
      const size_t ro = (size_t)(mg + r) * 256;
#pragma unroll
      for (int j = 0; j < 4; ++j) {
        float v = acc[i][j][r];
        Y[ro + colb + j * 16 + lm] = f2bf(v);
        lsum[j] += v; lsq[j] += v * v;
      }
    }
  }
#pragma unroll
  for (int j = 0; j < 4; ++j) {
    atomicAdd(&csum[wn * 64 + j * 16 + lm], lsum[j]);
    atomicAdd(&csq[wn * 64 + j * 16 + lm], lsq[j]);
  }
  __syncthreads();
  if (t < 128) {
    ps[(size_t)bm * 256 + bn * 128 + t] = csum[t];
    pq[(size_t)bm * 256 + bn * 128 + t] = csq[t];
  }
}

// ---------------------------------------------------------------- BN finalize: a=gamma*rsqrt(var+eps), b=beta-mean*a
__global__ void bn_finalize_kernel(const float* __restrict__ ps, const float* __restrict__ pq,
                                   const float* __restrict__ gamma, const float* __restrict__ beta,
                                   float* __restrict__ ab, int C, int slots, float invN) {
  int c = threadIdx.x;
  if (c >= C) return;
  float s = 0.f, sq = 0.f;
  for (int i = 0; i < slots; ++i) { s += ps[(size_t)i * C + c]; sq += pq[(size_t)i * C + c]; }
  float mean = s * invN;
  float var = sq * invN - mean * mean;
  float a = gamma[c] * rsqrtf(var + 1e-5f);
  ab[c] = a;
  ab[C + c] = beta[c] - mean * a;
}

// ---------------------------------------------------------------- GEMM2: out = relu(bn1(Y1)) * W2^T, f32 out to d_out, + column stats
__device__ __forceinline__ uint4 bnrelu_pack(uint4 raw, const float* a1s, const float* b1s, int kb) {
  union { uint4 v; u16 s[8]; } u;
  u.v = raw;
#pragma unroll
  for (int e = 0; e < 8; ++e) {
    float f = fmaxf(bf2f(u.s[e]) * a1s[kb + e] + b1s[kb + e], 0.f);
    u.s[e] = f2bf(f);
  }
  return u.v;
}

__global__ __launch_bounds__(256) void gemm2_kernel(
    const u16* __restrict__ Yin, const u16* __restrict__ Wb,
    const float* __restrict__ ab1, float* __restrict__ out,
    float* __restrict__ ps, float* __restrict__ pq) {
  const int K = 256;
  __shared__ u16 As[128 * 40];
  __shared__ u16 Bs[128 * 40];
  __shared__ float a1s[256], b1s[256];
  __shared__ float csum[128];
  __shared__ float csq[128];

  const int t = threadIdx.x;
  const int bm = blockIdx.x;
  a1s[t] = ab1[t];
  b1s[t] = ab1[256 + t];

  const int w = t >> 6, l = t & 63;
  const int wm = w >> 1, wn = w & 1;
  const int lm = l & 15, q = l >> 4;
  const int m0 = t >> 2, qq = t & 3;

  f32x4 acc[4][4] = {};

  const u16* Ag = Yin + (size_t)bm * 128 * K;
  const u16* Bg = Wb;

  for (int k0 = 0; k0 < K; k0 += 32) {
    uint4 av0 = *(const uint4*)(Ag + (size_t)m0 * K + k0 + qq * 8);
    uint4 av1 = *(const uint4*)(Ag + (size_t)(m0 + 64) * K + k0 + qq * 8);
    uint4 bv0 = *(const uint4*)(Bg + (size_t)m0 * K + k0 + qq * 8);
    uint4 bv1 = *(const uint4*)(Bg + (size_t)(m0 + 64) * K + k0 + qq * 8);
    __syncthreads();
    const int kb = k0 + qq * 8;
    av0 = bnrelu_pack(av0, a1s, b1s, kb);
    av1 = bnrelu_pack(av1, a1s, b1s, kb);
    *(uint4*)&As[m0 * 40 + qq * 8] = av0;
    *(uint4*)&As[(m0 + 64) * 40 + qq * 8] = av1;
    *(uint4*)&Bs[m0 * 40 + qq * 8] = bv0;
    *(uint4*)&Bs[(m0 + 64) * 40 + qq * 8] = bv1;
    __syncthreads();
    bf16x8 af[4], bfv[4];
#pragma unroll
    for (int i = 0; i < 4; ++i)
      af[i] = *(const bf16x8*)&As[(wm * 64 + i * 16 + lm) * 40 + q * 8];
#pragma unroll
    for (int j = 0; j < 4; ++j)
      bfv[j] = *(const bf16x8*)&Bs[(wn * 64 + j * 16 + lm) * 40 + q * 8];
#pragma unroll
    for (int i = 0; i < 4; ++i)
#pragma unroll
      for (int j = 0; j < 4; ++j)
        acc[i][j] = __builtin_amdgcn_mfma_f32_16x16x32_bf16(af[i], bfv[j], acc[i][j], 0, 0, 0);
  }

  if (t < 128) { csum[t] = 0.f; csq[t] = 0.f; }
  __syncthreads();

  float lsum[4] = {0, 0, 0, 0}, lsq[4] = {0, 0, 0, 0};
  const int colb = wn * 64;
#pragma unroll
  for (int i = 0; i < 4; ++i) {
    const int mg = bm * 128 + wm * 64 + i * 16 + q * 4;
#pragma unroll
    for (int r = 0; r < 4; ++r) {
      const size_t ro = (size_t)(mg + r) * 128;
#pragma unroll
      for (int j = 0; j < 4; ++j) {
        float v = acc[i][j][r];
        out[ro + colb + j * 16 + lm] = v;
        lsum[j] += v; lsq[j] += v * v;
      }
    }
  }
#pragma unroll
  for (int j = 0; j < 4; ++j) {
    atomicAdd(&csum[wn * 64 + j * 16 + lm], lsum[j]);
    atomicAdd(&csq[wn * 64 + j * 16 + lm], lsq[j]);
  }
  __syncthreads();
  if (t < 128) {
    ps[(size_t)bm * 128 + t] = csum[t];
    pq[(size_t)bm * 128 + t] = csq[t];
  }
}

// ---------------------------------------------------------------- final BN2+ReLU in place on d_out
__global__ __launch_bounds__(256) void bn_relu_out_kernel(float* __restrict__ out,
                                                          const float* __restrict__ ab2) {
  int idx = blockIdx.x * 256 + threadIdx.x;   // 8192*256 = 2097152 = exactly out_size/4
  float4* o4 = (float4*)out;
  float4 v = o4[idx];
  int c = (idx * 4) & 127;
  v.x = fmaxf(v.x * ab2[c + 0] + ab2[128 + c + 0], 0.f);
  v.y = fmaxf(v.y * ab2[c + 1] + ab2[128 + c + 1], 0.f);
  v.z = fmaxf(v.z * ab2[c + 2] + ab2[128 + c + 2], 0.f);
  v.w = fmaxf(v.w * ab2[c + 3] + ab2[128 + c + 3], 0.f);
  o4[idx] = v;
}

extern "C" void kernel_launch(void* const* d_in, const int* in_sizes, int n_in,
                              void* d_out, int out_size, void* d_ws, size_t ws_size,
                              hipStream_t stream) {
  const float* txyz  = (const float*)d_in[0];
  const float* sxyz  = (const float*)d_in[1];
  const float* sfeat = (const float*)d_in[2];
  const float* skip  = (const float*)d_in[3];
  const float* W1    = (const float*)d_in[4];
  const float* g1    = (const float*)d_in[5];
  const float* be1   = (const float*)d_in[6];
  const float* W2    = (const float*)d_in[7];
  const float* g2    = (const float*)d_in[8];
  const float* be2   = (const float*)d_in[9];
  float* out = (float*)d_out;

  char* ws = (char*)d_ws;
  u16*   Xb  = (u16*)(ws + 0ull);                 // 65536*384*2 = 50331648
  u16*   Y1  = (u16*)(ws + 50331648ull);          // 65536*256*2 = 33554432
  u16*   W1b = (u16*)(ws + 83886080ull);          // 196608
  u16*   W2b = (u16*)(ws + 84082688ull);          // 65536
  float* ps1 = (float*)(ws + 84148224ull);        // 512*256*4
  float* pq1 = (float*)(ws + 84672512ull);        // 512*256*4
  float* ps2 = (float*)(ws + 85196800ull);        // 512*128*4
  float* pq2 = (float*)(ws + 85458944ull);        // 512*128*4
  float* ab1 = (float*)(ws + 85721088ull);        // 512*4
  float* ab2 = (float*)(ws + 85723136ull);        // 256*4

  conv_w_kernel<<<512, 256, 0, stream>>>(W1, W2, W1b, W2b);
  interp_kernel<<<1024, 256, 0, stream>>>(txyz, sxyz, sfeat, skip, Xb);
  gemm1_kernel<<<dim3(512, 2), 256, 0, stream>>>(Xb, W1b, Y1, ps1, pq1);
  bn_finalize_kernel<<<1, 256, 0, stream>>>(ps1, pq1, g1, be1, ab1, 256, 512, 1.0f / 65536.0f);
  gemm2_kernel<<<512, 256, 0, stream>>>(Y1, W2b, ab1, out, ps2, pq2);
  bn_finalize_kernel<<<1, 256, 0, stream>>>(ps2, pq2, g2, be2, ab2, 128, 512, 1.0f / 65536.0f);
  bn_relu_out_kernel<<<8192, 256, 0, stream>>>(out, ab2);
}

// Round 2
// 392.825 us; speedup vs baseline: 1.6995x; 1.6995x over previous
//
#include <hip/hip_runtime.h>

typedef unsigned short u16;
typedef unsigned int u32;

typedef __bf16 bf16x8 __attribute__((ext_vector_type(8)));
typedef float f32x4 __attribute__((ext_vector_type(4)));

__device__ __forceinline__ u16 f2bf(float f) {
  u32 u = __float_as_uint(f);
  u = u + 0x7fffu + ((u >> 16) & 1u);
  return (u16)(u >> 16);
}
__device__ __forceinline__ float bf2f(u16 u) {
  return __uint_as_float(((u32)u) << 16);
}

// strict-< insertion keeps earliest index on ties (matches jax.lax.top_k)
__device__ __forceinline__ void ins3(float d, int s,
                                     float& d0, float& d1, float& d2,
                                     int& i0, int& i1, int& i2) {
  if (d < d2) {
    if (d < d1) {
      d2 = d1; i2 = i1;
      if (d < d0) { d1 = d0; i1 = i0; d0 = d; i0 = s; }
      else        { d1 = d; i1 = s; }
    } else { d2 = d; i2 = s; }
  }
}

// ---------------------------------------------------------------- weights->bf16 + zero BN stat accumulators
__global__ __launch_bounds__(256) void conv_w_kernel(
    const float* __restrict__ W1, const float* __restrict__ W2,
    u16* __restrict__ W1b, u16* __restrict__ W2b, float* __restrict__ stats) {
  int i = blockIdx.x * 256 + threadIdx.x;      // 512 blocks * 256 = 131072 exactly
  if (i < 98304) W1b[i] = f2bf(W1[i]);
  else           W2b[i - 98304] = f2bf(W2[i - 98304]);
  if (i < 768) stats[i] = 0.f;                 // gs1[256] gq1[256] gs2[128] gq2[128]
}

// ---------------------------------------------------------------- 3NN: indices + weights per point
// Block: 256 threads = 64 target points x 4 sub-scans of 256 sources.
// Grid: 16 batches * 64 = 1024 blocks. Output nn[point*2+{0,1}] = (idx.xyz, -), (w.xyz, -)
__global__ __launch_bounds__(256) void knn_kernel(
    const float* __restrict__ txyz, const float* __restrict__ sxyz,
    float4* __restrict__ nn) {
  __shared__ float4 sP[1028];      // padded: index s + (s>>8) -> 4 sub-chunks on disjoint banks
  __shared__ float  md[64 * 12];
  __shared__ int    mi[64 * 12];

  const int t = threadIdx.x;
  const int b = blockIdx.x >> 6;
  const int n0 = (blockIdx.x & 63) << 6;

  const float* sb = sxyz + (size_t)b * 1024 * 3;
  for (int i = t; i < 1024; i += 256) {
    float x = sb[i * 3 + 0], y = sb[i * 3 + 1], z = sb[i * 3 + 2];
    float r2 = __fadd_rn(__fadd_rn(__fmul_rn(x, x), __fmul_rn(y, y)), __fmul_rn(z, z));
    sP[i + (i >> 8)] = make_float4(x, y, z, r2);
  }
  __syncthreads();

  const int p = t >> 2, sub = t & 3;
  const int n = n0 + p;
  const float* tb = txyz + ((size_t)b * 4096 + n) * 3;
  const float t0 = tb[0], t1 = tb[1], t2 = tb[2];
  const float q2 = __fadd_rn(__fadd_rn(__fmul_rn(t0, t0), __fmul_rn(t1, t1)), __fmul_rn(t2, t2));

  float d0 = 1e30f, d1 = 1e30f, d2 = 1e30f;
  int i0 = 0, i1 = 0, i2 = 0;
  const int sbeg = sub * 256;
#pragma unroll 4
  for (int s = sbeg; s < sbeg + 256; ++s) {
    float4 sp = sP[s + (s >> 8)];
    float c = __fmul_rn(t0, sp.x);
    c = __fadd_rn(c, __fmul_rn(t1, sp.y));
    c = __fadd_rn(c, __fmul_rn(t2, sp.z));
    // matches ref: (q2 + r2) - 2*cross, then max(.,0); no FMA contraction
    float d = __fadd_rn(__fadd_rn(q2, sp.w), __fmul_rn(-2.0f, c));
    d = fmaxf(d, 0.0f);
    ins3(d, s, d0, d1, d2, i0, i1, i2);
  }
  md[p * 12 + sub * 3 + 0] = d0; md[p * 12 + sub * 3 + 1] = d1; md[p * 12 + sub * 3 + 2] = d2;
  mi[p * 12 + sub * 3 + 0] = i0; mi[p * 12 + sub * 3 + 1] = i1; mi[p * 12 + sub * 3 + 2] = i2;
  __syncthreads();

  if (sub == 0) {
    float D0 = 1e30f, D1 = 1e30f, D2 = 1e30f;
    int I0 = 0, I1 = 0, I2 = 0;
    for (int ss = 0; ss < 4; ++ss)          // ascending chunk => earliest index wins ties
      for (int k = 0; k < 3; ++k)
        ins3(md[p * 12 + ss * 3 + k], mi[p * 12 + ss * 3 + k], D0, D1, D2, I0, I1, I2);
    int idxs[3] = {I0, I1, I2};
    float w[3], wsum = 0.f;
    for (int k = 0; k < 3; ++k) {
      float4 sp = sP[idxs[k] + (idxs[k] >> 8)];
      float dx = t0 - sp.x, dy = t1 - sp.y, dz = t2 - sp.z;
      float dd = __fadd_rn(__fadd_rn(__fmul_rn(dx, dx), __fmul_rn(dy, dy)), __fmul_rn(dz, dz));
      w[k] = 1.0f / (dd + 1e-8f);
      wsum += w[k];
    }
    float inv = 1.0f / wsum;
    size_t pt = (size_t)b * 4096 + n;
    nn[pt * 2 + 0] = make_float4(__int_as_float(I0), __int_as_float(I1), __int_as_float(I2), 0.f);
    nn[pt * 2 + 1] = make_float4(w[0] * inv, w[1] * inv, w[2] * inv, 0.f);
  }
}

// ---------------------------------------------------------------- gather + concat -> Xb (bf16)
// One wave per point. 16384 blocks x 256 threads. XCD swizzle: xcd = blk&7 sees
// only batches {xcd, xcd+8} -> 2MB sfeat working set per XCD L2.
__global__ __launch_bounds__(256) void gather_kernel(
    const float4* __restrict__ nn, const float* __restrict__ sfeat,
    const float* __restrict__ skip, u16* __restrict__ Xb) {
  const int raw = blockIdx.x;
  const int xcd = raw & 7;
  const int i = raw >> 3;                 // 0..2047
  const int b = xcd + ((i & 1) << 3);     // batch 0..15
  const int pg = i >> 1;                  // 0..1023
  const int w = threadIdx.x >> 6, l = threadIdx.x & 63;

  const size_t n = (size_t)b * 4096 + pg * 4 + w;
  float4 nni = nn[n * 2 + 0];
  float4 nnw = nn[n * 2 + 1];
  const int j0 = __float_as_int(nni.x), j1 = __float_as_int(nni.y), j2 = __float_as_int(nni.z);
  const float w0 = nnw.x, w1 = nnw.y, w2 = nnw.z;

  const float4* fb = (const float4*)(sfeat + (size_t)b * 1024 * 256);
  float4 a = fb[j0 * 64 + l];
  float4 bb = fb[j1 * 64 + l];
  float4 c = fb[j2 * 64 + l];
  float4 f;
  f.x = w0 * a.x + w1 * bb.x + w2 * c.x;
  f.y = w0 * a.y + w1 * bb.y + w2 * c.y;
  f.z = w0 * a.z + w1 * bb.z + w2 * c.z;
  f.w = w0 * a.w + w1 * bb.w + w2 * c.w;
  ushort4 o;
  o.x = f2bf(f.x); o.y = f2bf(f.y); o.z = f2bf(f.z); o.w = f2bf(f.w);
  *(ushort4*)(Xb + n * 384 + 4 * l) = o;

  if (l < 32) {
    const float4* sk = (const float4*)(skip + n * 128);
    float4 s4 = sk[l];
    ushort4 so;
    so.x = f2bf(s4.x); so.y = f2bf(s4.y); so.z = f2bf(s4.z); so.w = f2bf(s4.w);
    *(ushort4*)(Xb + n * 384 + 256 + 4 * l) = so;
  }
}

// ---------------------------------------------------------------- GEMM1: Y1 = X(65536x384) * W1^T(256x384), bf16 MFMA, + column stats (atomic)
__global__ __launch_bounds__(256) void gemm1_kernel(
    const u16* __restrict__ X, const u16* __restrict__ Wb,
    u16* __restrict__ Y, float* __restrict__ gs, float* __restrict__ gq) {
  const int K = 384;
  __shared__ u16 As[128 * 40];
  __shared__ u16 Bs[128 * 40];
  __shared__ float csum[128];
  __shared__ float csq[128];

  const int t = threadIdx.x;
  const int bm = blockIdx.x, bn = blockIdx.y;
  const int w = t >> 6, l = t & 63;
  const int wm = w >> 1, wn = w & 1;
  const int lm = l & 15, q = l >> 4;
  const int m0 = t >> 2, qq = t & 3;

  f32x4 acc[4][4] = {};

  const u16* Ag = X + (size_t)bm * 128 * K;
  const u16* Bg = Wb + (size_t)bn * 128 * K;

  for (int k0 = 0; k0 < K; k0 += 32) {
    uint4 av0 = *(const uint4*)(Ag + (size_t)m0 * K + k0 + qq * 8);
    uint4 av1 = *(const uint4*)(Ag + (size_t)(m0 + 64) * K + k0 + qq * 8);
    uint4 bv0 = *(const uint4*)(Bg + (size_t)m0 * K + k0 + qq * 8);
    uint4 bv1 = *(const uint4*)(Bg + (size_t)(m0 + 64) * K + k0 + qq * 8);
    __syncthreads();
    *(uint4*)&As[m0 * 40 + qq * 8] = av0;
    *(uint4*)&As[(m0 + 64) * 40 + qq * 8] = av1;
    *(uint4*)&Bs[m0 * 40 + qq * 8] = bv0;
    *(uint4*)&Bs[(m0 + 64) * 40 + qq * 8] = bv1;
    __syncthreads();
    bf16x8 af[4], bfv[4];
#pragma unroll
    for (int i = 0; i < 4; ++i)
      af[i] = *(const bf16x8*)&As[(wm * 64 + i * 16 + lm) * 40 + q * 8];
#pragma unroll
    for (int j = 0; j < 4; ++j)
      bfv[j] = *(const bf16x8*)&Bs[(wn * 64 + j * 16 + lm) * 40 + q * 8];
#pragma unroll
    for (int i = 0; i < 4; ++i)
#pragma unroll
      for (int j = 0; j < 4; ++j)
        acc[i][j] = __builtin_amdgcn_mfma_f32_16x16x32_bf16(af[i], bfv[j], acc[i][j], 0, 0, 0);
  }

  if (t < 128) { csum[t] = 0.f; csq[t] = 0.f; }
  __syncthreads();

  float lsum[4] = {0, 0, 0, 0}, lsq[4] = {0, 0, 0, 0};
  const int colb = bn * 128 + wn * 64;
#pragma unroll
  for (int i = 0; i < 4; ++i) {
    const int mg = bm * 128 + wm * 64 + i * 16 + q * 4;
#pragma unroll
    for (int r = 0; r < 4; ++r) {
      const size_t ro = (size_t)(mg + r) * 256;
#pragma unroll
      for (int j = 0; j < 4; ++j) {
        float v = acc[i][j][r];
        Y[ro + colb + j * 16 + lm] = f2bf(v);
        lsum[j] += v; lsq[j] += v * v;
      }
    }
  }
#pragma unroll
  for (int j = 0; j < 4; ++j) {
    atomicAdd(&csum[wn * 64 + j * 16 + lm], lsum[j]);
    atomicAdd(&csq[wn * 64 + j * 16 + lm], lsq[j]);
  }
  __syncthreads();
  if (t < 128) {
    atomicAdd(&gs[bn * 128 + t], csum[t]);
    atomicAdd(&gq[bn * 128 + t], csq[t]);
  }
}

// ---------------------------------------------------------------- BN finalize (trivial): a=gamma*rsqrt(var+eps), b=beta-mean*a
__global__ void bn_finalize_kernel(const float* __restrict__ stats,
                                   const float* __restrict__ gamma, const float* __restrict__ beta,
                                   float* __restrict__ ab, int C, float invN) {
  int c = threadIdx.x;
  if (c >= C) return;
  float mean = stats[c] * invN;
  float var = stats[C + c] * invN - mean * mean;
  float a = gamma[c] * rsqrtf(var + 1e-5f);
  ab[c] = a;
  ab[C + c] = beta[c] - mean * a;
}

// ---------------------------------------------------------------- GEMM2: out = relu(bn1(Y1)) * W2^T, f32 out to d_out, + column stats (atomic)
__device__ __forceinline__ uint4 bnrelu_pack(uint4 raw, const float* a1s, const float* b1s, int kb) {
  union { uint4 v; u16 s[8]; } u;
  u.v = raw;
#pragma unroll
  for (int e = 0; e < 8; ++e) {
    float f = fmaxf(bf2f(u.s[e]) * a1s[kb + e] + b1s[kb + e], 0.f);
    u.s[e] = f2bf(f);
  }
  return u.v;
}

__global__ __launch_bounds__(256) void gemm2_kernel(
    const u16* __restrict__ Yin, const u16* __restrict__ Wb,
    const float* __restrict__ ab1, float* __restrict__ out,
    float* __restrict__ gs, float* __restrict__ gq) {
  const int K = 256;
  __shared__ u16 As[128 * 40];
  __shared__ u16 Bs[128 * 40];
  __shared__ float a1s[256], b1s[256];
  __shared__ float csum[128];
  __shared__ float csq[128];

  const int t = threadIdx.x;
  const int bm = blockIdx.x;
  a1s[t] = ab1[t];
  b1s[t] = ab1[256 + t];

  const int w = t >> 6, l = t & 63;
  const int wm = w >> 1, wn = w & 1;
  const int lm = l & 15, q = l >> 4;
  const int m0 = t >> 2, qq = t & 3;

  f32x4 acc[4][4] = {};

  const u16* Ag = Yin + (size_t)bm * 128 * K;
  const u16* Bg = Wb;

  for (int k0 = 0; k0 < K; k0 += 32) {
    uint4 av0 = *(const uint4*)(Ag + (size_t)m0 * K + k0 + qq * 8);
    uint4 av1 = *(const uint4*)(Ag + (size_t)(m0 + 64) * K + k0 + qq * 8);
    uint4 bv0 = *(const uint4*)(Bg + (size_t)m0 * K + k0 + qq * 8);
    uint4 bv1 = *(const uint4*)(Bg + (size_t)(m0 + 64) * K + k0 + qq * 8);
    __syncthreads();
    const int kb = k0 + qq * 8;
    av0 = bnrelu_pack(av0, a1s, b1s, kb);
    av1 = bnrelu_pack(av1, a1s, b1s, kb);
    *(uint4*)&As[m0 * 40 + qq * 8] = av0;
    *(uint4*)&As[(m0 + 64) * 40 + qq * 8] = av1;
    *(uint4*)&Bs[m0 * 40 + qq * 8] = bv0;
    *(uint4*)&Bs[(m0 + 64) * 40 + qq * 8] = bv1;
    __syncthreads();
    bf16x8 af[4], bfv[4];
#pragma unroll
    for (int i = 0; i < 4; ++i)
      af[i] = *(const bf16x8*)&As[(wm * 64 + i * 16 + lm) * 40 + q * 8];
#pragma unroll
    for (int j = 0; j < 4; ++j)
      bfv[j] = *(const bf16x8*)&Bs[(wn * 64 + j * 16 + lm) * 40 + q * 8];
#pragma unroll
    for (int i = 0; i < 4; ++i)
#pragma unroll
      for (int j = 0; j < 4; ++j)
        acc[i][j] = __builtin_amdgcn_mfma_f32_16x16x32_bf16(af[i], bfv[j], acc[i][j], 0, 0, 0);
  }

  if (t < 128) { csum[t] = 0.f; csq[t] = 0.f; }
  __syncthreads();

  float lsum[4] = {0, 0, 0, 0}, lsq[4] = {0, 0, 0, 0};
  const int colb = wn * 64;
#pragma unroll
  for (int i = 0; i < 4; ++i) {
    const int mg = bm * 128 + wm * 64 + i * 16 + q * 4;
#pragma unroll
    for (int r = 0; r < 4; ++r) {
      const size_t ro = (size_t)(mg + r) * 128;
#pragma unroll
      for (int j = 0; j < 4; ++j) {
        float v = acc[i][j][r];
        out[ro + colb + j * 16 + lm] = v;
        lsum[j] += v; lsq[j] += v * v;
      }
    }
  }
#pragma unroll
  for (int j = 0; j < 4; ++j) {
    atomicAdd(&csum[wn * 64 + j * 16 + lm], lsum[j]);
    atomicAdd(&csq[wn * 64 + j * 16 + lm], lsq[j]);
  }
  __syncthreads();
  if (t < 128) {
    atomicAdd(&gs[t], csum[t]);
    atomicAdd(&gq[t], csq[t]);
  }
}

// ---------------------------------------------------------------- final BN2+ReLU in place on d_out
__global__ __launch_bounds__(256) void bn_relu_out_kernel(float* __restrict__ out,
                                                          const float* __restrict__ ab2) {
  int idx = blockIdx.x * 256 + threadIdx.x;   // 8192*256 = 2097152 = exactly out_size/4
  float4* o4 = (float4*)out;
  float4 v = o4[idx];
  int c = (idx * 4) & 127;
  v.x = fmaxf(v.x * ab2[c + 0] + ab2[128 + c + 0], 0.f);
  v.y = fmaxf(v.y * ab2[c + 1] + ab2[128 + c + 1], 0.f);
  v.z = fmaxf(v.z * ab2[c + 2] + ab2[128 + c + 2], 0.f);
  v.w = fmaxf(v.w * ab2[c + 3] + ab2[128 + c + 3], 0.f);
  o4[idx] = v;
}

extern "C" void kernel_launch(void* const* d_in, const int* in_sizes, int n_in,
                              void* d_out, int out_size, void* d_ws, size_t ws_size,
                              hipStream_t stream) {
  const float* txyz  = (const float*)d_in[0];
  const float* sxyz  = (const float*)d_in[1];
  const float* sfeat = (const float*)d_in[2];
  const float* skip  = (const float*)d_in[3];
  const float* W1    = (const float*)d_in[4];
  const float* g1    = (const float*)d_in[5];
  const float* be1   = (const float*)d_in[6];
  const float* W2    = (const float*)d_in[7];
  const float* g2    = (const float*)d_in[8];
  const float* be2   = (const float*)d_in[9];
  float* out = (float*)d_out;

  char* ws = (char*)d_ws;
  u16*    Xb  = (u16*)(ws + 0ull);                // 65536*384*2 = 50331648
  u16*    Y1  = (u16*)(ws + 50331648ull);         // 65536*256*2 = 33554432
  float4* nnd = (float4*)(ws + 50331648ull);      // 65536*32 = 2097152 (overlaps Y1: nn consumed before Y1 written)
  u16*    W1b = (u16*)(ws + 83886080ull);         // 196608
  u16*    W2b = (u16*)(ws + 84082688ull);         // 65536
  float*  stats = (float*)(ws + 84148224ull);     // 768*4 = 3072: gs1[256] gq1[256] gs2[128] gq2[128]
  float*  ab1 = (float*)(ws + 84151296ull);       // 512*4
  float*  ab2 = (float*)(ws + 84153344ull);       // 256*4

  conv_w_kernel<<<512, 256, 0, stream>>>(W1, W2, W1b, W2b, stats);
  knn_kernel<<<1024, 256, 0, stream>>>(txyz, sxyz, nnd);
  gather_kernel<<<16384, 256, 0, stream>>>(nnd, sfeat, skip, Xb);
  gemm1_kernel<<<dim3(512, 2), 256, 0, stream>>>(Xb, W1b, Y1, stats, stats + 256);
  bn_finalize_kernel<<<1, 256, 0, stream>>>(stats, g1, be1, ab1, 256, 1.0f / 65536.0f);
  gemm2_kernel<<<512, 256, 0, stream>>>(Y1, W2b, ab1, out, stats + 512, stats + 640);
  bn_finalize_kernel<<<1, 128, 0, stream>>>(stats + 512, g2, be2, ab2, 128, 1.0f / 65536.0f);
  bn_relu_out_kernel<<<8192, 256, 0, stream>>>(out, ab2);
}

// Round 3
// 279.560 us; speedup vs baseline: 2.3881x; 1.4052x over previous
//
#include <hip/hip_runtime.h>

typedef unsigned short u16;
typedef unsigned int u32;

typedef __bf16 bf16x8 __attribute__((ext_vector_type(8)));
typedef float f32x4 __attribute__((ext_vector_type(4)));

__device__ __forceinline__ u16 f2bf(float f) {
  u32 u = __float_as_uint(f);
  u = u + 0x7fffu + ((u >> 16) & 1u);
  return (u16)(u >> 16);
}
__device__ __forceinline__ float bf2f(u16 u) {
  return __uint_as_float(((u32)u) << 16);
}

// strict-< insertion keeps earliest index on ties (matches jax.lax.top_k)
__device__ __forceinline__ void ins3(float d, int s,
                                     float& d0, float& d1, float& d2,
                                     int& i0, int& i1, int& i2) {
  if (d < d2) {
    if (d < d1) {
      d2 = d1; i2 = i1;
      if (d < d0) { d1 = d0; i1 = i0; d0 = d; i0 = s; }
      else        { d1 = d; i1 = s; }
    } else { d2 = d; i2 = s; }
  }
}

// branchless strict-< top-3 insert: 3 cmp + 10 cndmask
__device__ __forceinline__ void ins3b(float d, int s,
                                      float& d0, float& d1, float& d2,
                                      int& i0, int& i1, int& i2) {
  bool c2 = d < d2, c1 = d < d1, c0 = d < d0;
  d2 = c1 ? d1 : (c2 ? d : d2);
  i2 = c1 ? i1 : (c2 ? s : i2);
  d1 = c0 ? d0 : (c1 ? d : d1);
  i1 = c0 ? i0 : (c1 ? s : i1);
  d0 = c0 ? d : d0;
  i0 = c0 ? s : i0;
}

// ---------------------------------------------------------------- weights->bf16 + zero BN stat accumulators
__global__ __launch_bounds__(256) void conv_w_kernel(
    const float* __restrict__ W1, const float* __restrict__ W2,
    u16* __restrict__ W1b, u16* __restrict__ W2b, float* __restrict__ stats) {
  int i = blockIdx.x * 256 + threadIdx.x;      // 512 blocks * 256 = 131072 exactly
  if (i < 98304) W1b[i] = f2bf(W1[i]);
  else           W2b[i - 98304] = f2bf(W2[i - 98304]);
  if (i < 768) stats[i] = 0.f;                 // gs1[256] gq1[256] gs2[128] gq2[128]
}

// ---------------------------------------------------------------- 3NN: indices + weights per point
// Block: 256 threads = 64 target points x 4 sub-scans of 256 sources.
// Each sub-scan runs two independent 128-source streams (ILP on the
// cmp->cndmask chain); contiguous split keeps index-order tie-break exact.
__global__ __launch_bounds__(256) void knn_kernel(
    const float* __restrict__ txyz, const float* __restrict__ sxyz,
    float4* __restrict__ nn) {
  __shared__ float4 sP[1028];      // padded: index s + (s>>8) -> 4 sub-chunks on disjoint banks
  __shared__ float  md[64 * 12];
  __shared__ int    mi[64 * 12];

  const int t = threadIdx.x;
  const int b = blockIdx.x >> 6;
  const int n0 = (blockIdx.x & 63) << 6;

  const float* sb = sxyz + (size_t)b * 1024 * 3;
  for (int i = t; i < 1024; i += 256) {
    float x = sb[i * 3 + 0], y = sb[i * 3 + 1], z = sb[i * 3 + 2];
    float r2 = __fadd_rn(__fadd_rn(__fmul_rn(x, x), __fmul_rn(y, y)), __fmul_rn(z, z));
    sP[i + (i >> 8)] = make_float4(x, y, z, r2);
  }
  __syncthreads();

  const int p = t >> 2, sub = t & 3;
  const int n = n0 + p;
  const float* tb = txyz + ((size_t)b * 4096 + n) * 3;
  const float t0 = tb[0], t1 = tb[1], t2 = tb[2];
  const float q2 = __fadd_rn(__fadd_rn(__fmul_rn(t0, t0), __fmul_rn(t1, t1)), __fmul_rn(t2, t2));

  float d0a = 1e30f, d1a = 1e30f, d2a = 1e30f;
  int   i0a = 0, i1a = 0, i2a = 0;
  float d0b = 1e30f, d1b = 1e30f, d2b = 1e30f;
  int   i0b = 0, i1b = 0, i2b = 0;
  const int sbeg = sub * 256;

#pragma unroll 4
  for (int off = 0; off < 128; ++off) {
    const int sa = sbeg + off;
    const int sb2 = sbeg + 128 + off;
    float4 pa = sP[sa + (sa >> 8)];
    float4 pb = sP[sb2 + (sb2 >> 8)];

    float ca = __fmul_rn(t0, pa.x);
    ca = __fadd_rn(ca, __fmul_rn(t1, pa.y));
    ca = __fadd_rn(ca, __fmul_rn(t2, pa.z));
    float da = __fadd_rn(__fadd_rn(q2, pa.w), __fmul_rn(-2.0f, ca));
    da = fmaxf(da, 0.0f);

    float cb = __fmul_rn(t0, pb.x);
    cb = __fadd_rn(cb, __fmul_rn(t1, pb.y));
    cb = __fadd_rn(cb, __fmul_rn(t2, pb.z));
    float db = __fadd_rn(__fadd_rn(q2, pb.w), __fmul_rn(-2.0f, cb));
    db = fmaxf(db, 0.0f);

    ins3b(da, sa, d0a, d1a, d2a, i0a, i1a, i2a);
    ins3b(db, sb2, d0b, d1b, d2b, i0b, i1b, i2b);
  }
  // merge stream b into a: all b indices > all a indices, strict-< preserves tie-break
  ins3(d0b, i0b, d0a, d1a, d2a, i0a, i1a, i2a);
  ins3(d1b, i1b, d0a, d1a, d2a, i0a, i1a, i2a);
  ins3(d2b, i2b, d0a, d1a, d2a, i0a, i1a, i2a);

  md[p * 12 + sub * 3 + 0] = d0a; md[p * 12 + sub * 3 + 1] = d1a; md[p * 12 + sub * 3 + 2] = d2a;
  mi[p * 12 + sub * 3 + 0] = i0a; mi[p * 12 + sub * 3 + 1] = i1a; mi[p * 12 + sub * 3 + 2] = i2a;
  __syncthreads();

  if (sub == 0) {
    float D0 = 1e30f, D1 = 1e30f, D2 = 1e30f;
    int I0 = 0, I1 = 0, I2 = 0;
    for (int ss = 0; ss < 4; ++ss)          // ascending chunk => earliest index wins ties
      for (int k = 0; k < 3; ++k)
        ins3(md[p * 12 + ss * 3 + k], mi[p * 12 + ss * 3 + k], D0, D1, D2, I0, I1, I2);
    int idxs[3] = {I0, I1, I2};
    float w[3], wsum = 0.f;
    for (int k = 0; k < 3; ++k) {
      float4 sp = sP[idxs[k] + (idxs[k] >> 8)];
      float dx = t0 - sp.x, dy = t1 - sp.y, dz = t2 - sp.z;
      float dd = __fadd_rn(__fadd_rn(__fmul_rn(dx, dx), __fmul_rn(dy, dy)), __fmul_rn(dz, dz));
      w[k] = 1.0f / (dd + 1e-8f);
      wsum += w[k];
    }
    float inv = 1.0f / wsum;
    size_t pt = (size_t)b * 4096 + n;
    nn[pt * 2 + 0] = make_float4(__int_as_float(I0), __int_as_float(I1), __int_as_float(I2), 0.f);
    nn[pt * 2 + 1] = make_float4(w[0] * inv, w[1] * inv, w[2] * inv, 0.f);
  }
}

// ---------------------------------------------------------------- gather + concat -> Xb (bf16)
// One wave per point. 16384 blocks x 256 threads. XCD swizzle: xcd = blk&7 sees
// only batches {xcd, xcd+8} -> 2MB sfeat working set per XCD L2.
__global__ __launch_bounds__(256) void gather_kernel(
    const float4* __restrict__ nn, const float* __restrict__ sfeat,
    const float* __restrict__ skip, u16* __restrict__ Xb) {
  const int raw = blockIdx.x;
  const int xcd = raw & 7;
  const int i = raw >> 3;                 // 0..2047
  const int b = xcd + ((i & 1) << 3);     // batch 0..15
  const int pg = i >> 1;                  // 0..1023
  const int w = threadIdx.x >> 6, l = threadIdx.x & 63;

  const size_t n = (size_t)b * 4096 + pg * 4 + w;
  float4 nni = nn[n * 2 + 0];
  float4 nnw = nn[n * 2 + 1];
  const int j0 = __float_as_int(nni.x), j1 = __float_as_int(nni.y), j2 = __float_as_int(nni.z);
  const float w0 = nnw.x, w1 = nnw.y, w2 = nnw.z;

  const float4* fb = (const float4*)(sfeat + (size_t)b * 1024 * 256);
  float4 a = fb[j0 * 64 + l];
  float4 bb = fb[j1 * 64 + l];
  float4 c = fb[j2 * 64 + l];
  float4 f;
  f.x = w0 * a.x + w1 * bb.x + w2 * c.x;
  f.y = w0 * a.y + w1 * bb.y + w2 * c.y;
  f.z = w0 * a.z + w1 * bb.z + w2 * c.z;
  f.w = w0 * a.w + w1 * bb.w + w2 * c.w;
  ushort4 o;
  o.x = f2bf(f.x); o.y = f2bf(f.y); o.z = f2bf(f.z); o.w = f2bf(f.w);
  *(ushort4*)(Xb + n * 384 + 4 * l) = o;

  if (l < 32) {
    const float4* sk = (const float4*)(skip + n * 128);
    float4 s4 = sk[l];
    ushort4 so;
    so.x = f2bf(s4.x); so.y = f2bf(s4.y); so.z = f2bf(s4.z); so.w = f2bf(s4.w);
    *(ushort4*)(Xb + n * 384 + 256 + 4 * l) = so;
  }
}

// ---------------------------------------------------------------- GEMM1: Y1 = X(65536x384) * W1^T(256x384), bf16 MFMA, + column stats (atomic)
__global__ __launch_bounds__(256) void gemm1_kernel(
    const u16* __restrict__ X, const u16* __restrict__ Wb,
    u16* __restrict__ Y, float* __restrict__ gs, float* __restrict__ gq) {
  const int K = 384;
  __shared__ u16 As[128 * 40];
  __shared__ u16 Bs[128 * 40];
  __shared__ float csum[128];
  __shared__ float csq[128];

  const int t = threadIdx.x;
  const int bm = blockIdx.x, bn = blockIdx.y;
  const int w = t >> 6, l = t & 63;
  const int wm = w >> 1, wn = w & 1;
  const int lm = l & 15, q = l >> 4;
  const int m0 = t >> 2, qq = t & 3;

  f32x4 acc[4][4] = {};

  const u16* Ag = X + (size_t)bm * 128 * K;
  const u16* Bg = Wb + (size_t)bn * 128 * K;

  for (int k0 = 0; k0 < K; k0 += 32) {
    uint4 av0 = *(const uint4*)(Ag + (size_t)m0 * K + k0 + qq * 8);
    uint4 av1 = *(const uint4*)(Ag + (size_t)(m0 + 64) * K + k0 + qq * 8);
    uint4 bv0 = *(const uint4*)(Bg + (size_t)m0 * K + k0 + qq * 8);
    uint4 bv1 = *(const uint4*)(Bg + (size_t)(m0 + 64) * K + k0 + qq * 8);
    __syncthreads();
    *(uint4*)&As[m0 * 40 + qq * 8] = av0;
    *(uint4*)&As[(m0 + 64) * 40 + qq * 8] = av1;
    *(uint4*)&Bs[m0 * 40 + qq * 8] = bv0;
    *(uint4*)&Bs[(m0 + 64) * 40 + qq * 8] = bv1;
    __syncthreads();
    bf16x8 af[4], bfv[4];
#pragma unroll
    for (int i = 0; i < 4; ++i)
      af[i] = *(const bf16x8*)&As[(wm * 64 + i * 16 + lm) * 40 + q * 8];
#pragma unroll
    for (int j = 0; j < 4; ++j)
      bfv[j] = *(const bf16x8*)&Bs[(wn * 64 + j * 16 + lm) * 40 + q * 8];
#pragma unroll
    for (int i = 0; i < 4; ++i)
#pragma unroll
      for (int j = 0; j < 4; ++j)
        acc[i][j] = __builtin_amdgcn_mfma_f32_16x16x32_bf16(af[i], bfv[j], acc[i][j], 0, 0, 0);
  }

  if (t < 128) { csum[t] = 0.f; csq[t] = 0.f; }
  __syncthreads();

  float lsum[4] = {0, 0, 0, 0}, lsq[4] = {0, 0, 0, 0};
  const int colb = bn * 128 + wn * 64;
#pragma unroll
  for (int i = 0; i < 4; ++i) {
    const int mg = bm * 128 + wm * 64 + i * 16 + q * 4;
#pragma unroll
    for (int r = 0; r < 4; ++r) {
      const size_t ro = (size_t)(mg + r) * 256;
#pragma unroll
      for (int j = 0; j < 4; ++j) {
        float v = acc[i][j][r];
        Y[ro + colb + j * 16 + lm] = f2bf(v);
        lsum[j] += v; lsq[j] += v * v;
      }
    }
  }
#pragma unroll
  for (int j = 0; j < 4; ++j) {
    atomicAdd(&csum[wn * 64 + j * 16 + lm], lsum[j]);
    atomicAdd(&csq[wn * 64 + j * 16 + lm], lsq[j]);
  }
  __syncthreads();
  if (t < 128) {
    atomicAdd(&gs[bn * 128 + t], csum[t]);
    atomicAdd(&gq[bn * 128 + t], csq[t]);
  }
}

// ---------------------------------------------------------------- BN finalize (trivial): a=gamma*rsqrt(var+eps), b=beta-mean*a
__global__ void bn_finalize_kernel(const float* __restrict__ stats,
                                   const float* __restrict__ gamma, const float* __restrict__ beta,
                                   float* __restrict__ ab, int C, float invN) {
  int c = threadIdx.x;
  if (c >= C) return;
  float mean = stats[c] * invN;
  float var = stats[C + c] * invN - mean * mean;
  float a = gamma[c] * rsqrtf(var + 1e-5f);
  ab[c] = a;
  ab[C + c] = beta[c] - mean * a;
}

// ---------------------------------------------------------------- GEMM2: out = relu(bn1(Y1)) * W2^T, f32 out to d_out, + column stats (atomic)
__device__ __forceinline__ uint4 bnrelu_pack(uint4 raw, const float* a1s, const float* b1s, int kb) {
  union { uint4 v; u16 s[8]; } u;
  u.v = raw;
#pragma unroll
  for (int e = 0; e < 8; ++e) {
    float f = fmaxf(bf2f(u.s[e]) * a1s[kb + e] + b1s[kb + e], 0.f);
    u.s[e] = f2bf(f);
  }
  return u.v;
}

__global__ __launch_bounds__(256) void gemm2_kernel(
    const u16* __restrict__ Yin, const u16* __restrict__ Wb,
    const float* __restrict__ ab1, float* __restrict__ out,
    float* __restrict__ gs, float* __restrict__ gq) {
  const int K = 256;
  __shared__ u16 As[128 * 40];
  __shared__ u16 Bs[128 * 40];
  __shared__ float a1s[256], b1s[256];
  __shared__ float csum[128];
  __shared__ float csq[128];

  const int t = threadIdx.x;
  const int bm = blockIdx.x;
  a1s[t] = ab1[t];
  b1s[t] = ab1[256 + t];

  const int w = t >> 6, l = t & 63;
  const int wm = w >> 1, wn = w & 1;
  const int lm = l & 15, q = l >> 4;
  const int m0 = t >> 2, qq = t & 3;

  f32x4 acc[4][4] = {};

  const u16* Ag = Yin + (size_t)bm * 128 * K;
  const u16* Bg = Wb;

  for (int k0 = 0; k0 < K; k0 += 32) {
    uint4 av0 = *(const uint4*)(Ag + (size_t)m0 * K + k0 + qq * 8);
    uint4 av1 = *(const uint4*)(Ag + (size_t)(m0 + 64) * K + k0 + qq * 8);
    uint4 bv0 = *(const uint4*)(Bg + (size_t)m0 * K + k0 + qq * 8);
    uint4 bv1 = *(const uint4*)(Bg + (size_t)(m0 + 64) * K + k0 + qq * 8);
    __syncthreads();
    const int kb = k0 + qq * 8;
    av0 = bnrelu_pack(av0, a1s, b1s, kb);
    av1 = bnrelu_pack(av1, a1s, b1s, kb);
    *(uint4*)&As[m0 * 40 + qq * 8] = av0;
    *(uint4*)&As[(m0 + 64) * 40 + qq * 8] = av1;
    *(uint4*)&Bs[m0 * 40 + qq * 8] = bv0;
    *(uint4*)&Bs[(m0 + 64) * 40 + qq * 8] = bv1;
    __syncthreads();
    bf16x8 af[4], bfv[4];
#pragma unroll
    for (int i = 0; i < 4; ++i)
      af[i] = *(const bf16x8*)&As[(wm * 64 + i * 16 + lm) * 40 + q * 8];
#pragma unroll
    for (int j = 0; j < 4; ++j)
      bfv[j] = *(const bf16x8*)&Bs[(wn * 64 + j * 16 + lm) * 40 + q * 8];
#pragma unroll
    for (int i = 0; i < 4; ++i)
#pragma unroll
      for (int j = 0; j < 4; ++j)
        acc[i][j] = __builtin_amdgcn_mfma_f32_16x16x32_bf16(af[i], bfv[j], acc[i][j], 0, 0, 0);
  }

  if (t < 128) { csum[t] = 0.f; csq[t] = 0.f; }
  __syncthreads();

  float lsum[4] = {0, 0, 0, 0}, lsq[4] = {0, 0, 0, 0};
  const int colb = wn * 64;
#pragma unroll
  for (int i = 0; i < 4; ++i) {
    const int mg = bm * 128 + wm * 64 + i * 16 + q * 4;
#pragma unroll
    for (int r = 0; r < 4; ++r) {
      const size_t ro = (size_t)(mg + r) * 128;
#pragma unroll
      for (int j = 0; j < 4; ++j) {
        float v = acc[i][j][r];
        out[ro + colb + j * 16 + lm] = v;
        lsum[j] += v; lsq[j] += v * v;
      }
    }
  }
#pragma unroll
  for (int j = 0; j < 4; ++j) {
    atomicAdd(&csum[wn * 64 + j * 16 + lm], lsum[j]);
    atomicAdd(&csq[wn * 64 + j * 16 + lm], lsq[j]);
  }
  __syncthreads();
  if (t < 128) {
    atomicAdd(&gs[t], csum[t]);
    atomicAdd(&gq[t], csq[t]);
  }
}

// ---------------------------------------------------------------- final BN2+ReLU in place on d_out
__global__ __launch_bounds__(256) void bn_relu_out_kernel(float* __restrict__ out,
                                                          const float* __restrict__ ab2) {
  int idx = blockIdx.x * 256 + threadIdx.x;   // 8192*256 = 2097152 = exactly out_size/4
  float4* o4 = (float4*)out;
  float4 v = o4[idx];
  int c = (idx * 4) & 127;
  v.x = fmaxf(v.x * ab2[c + 0] + ab2[128 + c + 0], 0.f);
  v.y = fmaxf(v.y * ab2[c + 1] + ab2[128 + c + 1], 0.f);
  v.z = fmaxf(v.z * ab2[c + 2] + ab2[128 + c + 2], 0.f);
  v.w = fmaxf(v.w * ab2[c + 3] + ab2[128 + c + 3], 0.f);
  o4[idx] = v;
}

extern "C" void kernel_launch(void* const* d_in, const int* in_sizes, int n_in,
                              void* d_out, int out_size, void* d_ws, size_t ws_size,
                              hipStream_t stream) {
  const float* txyz  = (const float*)d_in[0];
  const float* sxyz  = (const float*)d_in[1];
  const float* sfeat = (const float*)d_in[2];
  const float* skip  = (const float*)d_in[3];
  const float* W1    = (const float*)d_in[4];
  const float* g1    = (const float*)d_in[5];
  const float* be1   = (const float*)d_in[6];
  const float* W2    = (const float*)d_in[7];
  const float* g2    = (const float*)d_in[8];
  const float* be2   = (const float*)d_in[9];
  float* out = (float*)d_out;

  char* ws = (char*)d_ws;
  u16*    Xb  = (u16*)(ws + 0ull);                // 65536*384*2 = 50331648
  u16*    Y1  = (u16*)(ws + 50331648ull);         // 65536*256*2 = 33554432
  float4* nnd = (float4*)(ws + 50331648ull);      // 65536*32 = 2097152 (overlaps Y1: nn consumed before Y1 written)
  u16*    W1b = (u16*)(ws + 83886080ull);         // 196608
  u16*    W2b = (u16*)(ws + 84082688ull);         // 65536
  float*  stats = (float*)(ws + 84148224ull);     // 768*4 = 3072: gs1[256] gq1[256] gs2[128] gq2[128]
  float*  ab1 = (float*)(ws + 84151296ull);       // 512*4
  float*  ab2 = (float*)(ws + 84153344ull);       // 256*4

  conv_w_kernel<<<512, 256, 0, stream>>>(W1, W2, W1b, W2b, stats);
  knn_kernel<<<1024, 256, 0, stream>>>(txyz, sxyz, nnd);
  gather_kernel<<<16384, 256, 0, stream>>>(nnd, sfeat, skip, Xb);
  gemm1_kernel<<<dim3(512, 2), 256, 0, stream>>>(Xb, W1b, Y1, stats, stats + 256);
  bn_finalize_kernel<<<1, 256, 0, stream>>>(stats, g1, be1, ab1, 256, 1.0f / 65536.0f);
  gemm2_kernel<<<512, 256, 0, stream>>>(Y1, W2b, ab1, out, stats + 512, stats + 640);
  bn_finalize_kernel<<<1, 128, 0, stream>>>(stats + 512, g2, be2, ab2, 128, 1.0f / 65536.0f);
  bn_relu_out_kernel<<<8192, 256, 0, stream>>>(out, ab2);
}